// Round 1
// 512.837 us; speedup vs baseline: 1.0877x; 1.0877x over previous
//
#include <hip/hip_runtime.h>

namespace {
constexpr int kB = 64;
constexpr int kN = 8400;
constexpr int kMain = 8192;          // bitonic-sorted main segment per image
constexpr int kTail = kN - kMain;    // 208, sorted in-LDS inside nms
constexpr int kReg = 64;
constexpr int kCls = 80;
constexpr int kStride = kReg + kCls; // 144
constexpr int kMaxOut = 100;
constexpr float kScoreTh = 0.3f;
constexpr float kIouTh = 0.5f;
}

// ---------------------------------------------------------------------------
// Stage 1: coalesced decode (verified absmax 0.0). Block = 256 threads =
// 64 anchors x 4 sides; LDS staging; fused NMS key packing. UNCHANGED.
// ---------------------------------------------------------------------------
__global__ __launch_bounds__(256) void decode2_k(
    const float* __restrict__ preds,
    const float* __restrict__ anchors,
    float4* __restrict__ boxes,
    float* __restrict__ scores,
    int* __restrict__ labels,
    unsigned long long* __restrict__ keys)
{
    __shared__ float lds[64 * 148];
    const int tid = threadIdx.x;
    const size_t gbase = (size_t)blockIdx.x * 64;

    const float4* src = (const float4*)(preds + gbase * kStride);
    float4* l4 = (float4*)lds;
#pragma unroll
    for (int k = 0; k < 9; ++k) {
        int i = tid + k * 256;
        int row = i / 36, col = i - row * 36;
        l4[row * 37 + col] = src[i];
    }
    __syncthreads();

    const int a = tid >> 2, s = tid & 3;
    const float* rowp = lds + a * 148;

    float x[16];
    const float4* q = (const float4*)(rowp + s * 16);
#pragma unroll
    for (int j = 0; j < 4; ++j) ((float4*)x)[j] = q[j];
    float m = x[0];
#pragma unroll
    for (int j = 1; j < 16; ++j) m = fmaxf(m, x[j]);
    float se = 0.f, we = 0.f;
#pragma unroll
    for (int j = 0; j < 16; ++j) {
        float t = expf(x[j] - m);
        se += t;
        we += t * (float)j;
    }
    float d = we / se;

    const float4* cl = (const float4*)(rowp + kReg + s * 20);
    float bv = -3e38f; int bi = 0;
#pragma unroll
    for (int c = 0; c < 5; ++c) {
        float4 v = cl[c];
        int cb = s * 20 + 4 * c;
        if (v.x > bv) { bv = v.x; bi = cb; }
        if (v.y > bv) { bv = v.y; bi = cb + 1; }
        if (v.z > bv) { bv = v.z; bi = cb + 2; }
        if (v.w > bv) { bv = v.w; bi = cb + 3; }
    }

    const int lane = tid & 63;
    const int base = lane & ~3;
    float d0 = __shfl(d, base + 0, 64);
    float d1 = __shfl(d, base + 1, 64);
    float d2 = __shfl(d, base + 2, 64);
    float d3 = __shfl(d, base + 3, 64);
    float v1 = __shfl(bv, base + 1, 64); int i1 = __shfl(bi, base + 1, 64);
    float v2 = __shfl(bv, base + 2, 64); int i2 = __shfl(bi, base + 2, 64);
    float v3 = __shfl(bv, base + 3, 64); int i3 = __shfl(bi, base + 3, 64);

    if (s == 0) {
        float best = bv; int bl = bi;
        if (v1 > best) { best = v1; bl = i1; }
        if (v2 > best) { best = v2; bl = i2; }
        if (v3 > best) { best = v3; bl = i3; }

        size_t gi = gbase + a;
        int bimg = (int)(gi / kN);
        int n = (int)(gi - (size_t)bimg * kN);
        float4 av = ((const float4*)anchors)[n];
        float ah0 = av.z - av.x, ah1 = av.w - av.y;
        float c0 = (av.x + av.z) * 0.5f, c1 = (av.y + av.w) * 0.5f;
        float bc0 = (d2 - d0) * 0.5f * ah0 + c0;
        float bc1 = (d3 - d1) * 0.5f * ah1 + c1;
        float bh0 = (d2 + d0) * ah0;
        float bh1 = (d3 + d1) * ah1;
        boxes[gi] = make_float4(bc0 - bh0 * 0.5f, bc1 - bh1 * 0.5f,
                                bc0 + bh0 * 0.5f, bc1 + bh1 * 0.5f);
        scores[gi] = best;
        labels[gi] = bl;

        unsigned long long kkey = ~0ULL;
        if (best > kScoreTh) {
            unsigned u = __float_as_uint(best);
            unsigned o = u ^ ((u & 0x80000000u) ? 0xFFFFFFFFu : 0x80000000u);
            kkey = ((unsigned long long)(~o) << 32) | (unsigned)n;
        }
        keys[((size_t)bimg << 14) + n] = kkey;
    }
}

// ---------------------------------------------------------------------------
// Sort pipeline: the SAME bitonic network as the old single-block sort
// (comparator direction desc = (global_i & size) != 0, sizes 2..8192),
// partitioned into CU-saturating launches. Output is bit-identical, so the
// nms merge contract (main 8192 ascending) is preserved.
//
//   sortL_k      : 256 blocks, 2048-elem segments, sizes 2..2048 in LDS.
//   lm2_k<4096>  : 128 blocks, 4096-elem halves, strides 2048..1 (size 4096).
//   gce_k        : 1024 blocks, global CE for size 8192 / stride 4096.
//   lm2_k<8192>  : 128 blocks, 4096-elem halves, strides 2048..1 (ascending).
// ---------------------------------------------------------------------------
__global__ __launch_bounds__(512) void sortL_k(unsigned long long* __restrict__ keys)
{
    __shared__ unsigned long long lk[2048];          // 16 KB
    const int img = blockIdx.x >> 2, seg = blockIdx.x & 3;
    const int gofs = seg << 11;                      // global offset of segment
    unsigned long long* base = keys + ((size_t)img << 14) + gofs;

    for (int t = threadIdx.x; t < 2048; t += 512) lk[t] = base[t];
    __syncthreads();
    for (int size = 2; size <= 2048; size <<= 1) {
        for (int stride = size >> 1; stride > 0; stride >>= 1) {
#pragma unroll
            for (int p = 0; p < 2; ++p) {
                int n = threadIdx.x + (p << 9);      // 1024 pairs
                int i = ((n & ~(stride - 1)) << 1) | (n & (stride - 1));
                int j = i + stride;
                bool desc = ((gofs + i) & size) != 0;
                unsigned long long a = lk[i], c = lk[j];
                bool sw = desc ? (c > a) : (a > c);
                if (sw) { lk[i] = c; lk[j] = a; }
            }
            __syncthreads();
        }
    }
    for (int t = threadIdx.x; t < 2048; t += 512) base[t] = lk[t];
}

// size=8192, stride=4096: pairs (n, n+4096), ascending ((i & 8192) == 0).
__global__ __launch_bounds__(256) void gce_k(unsigned long long* __restrict__ keys)
{
    int tg = blockIdx.x * 256 + threadIdx.x;         // 64 img * 4096 pairs
    int img = tg >> 12;
    int n = tg & 4095;
    unsigned long long* base = keys + ((size_t)img << 14);
    unsigned long long a = base[n], c = base[n + 4096];
    if (a > c) { base[n] = c; base[n + 4096] = a; }
}

template <int SIZE>
__global__ __launch_bounds__(512) void lm2_k(unsigned long long* __restrict__ keys)
{
    __shared__ unsigned long long lk[4096];          // 32 KB
    const int img = blockIdx.x >> 1, half = blockIdx.x & 1;
    const int gofs = half << 12;
    unsigned long long* base = keys + ((size_t)img << 14) + gofs;

    for (int t = threadIdx.x; t < 4096; t += 512) lk[t] = base[t];
    __syncthreads();
    const bool desc = (gofs & SIZE) != 0;            // uniform per block
    for (int stride = 2048; stride > 0; stride >>= 1) {
#pragma unroll
        for (int p = 0; p < 4; ++p) {
            int n = threadIdx.x + (p << 9);          // 2048 pairs
            int i = ((n & ~(stride - 1)) << 1) | (n & (stride - 1));
            int j = i + stride;
            unsigned long long a = lk[i], c = lk[j];
            bool sw = desc ? (c > a) : (a > c);
            if (sw) { lk[i] = c; lk[j] = a; }
        }
        __syncthreads();
    }
    for (int t = threadIdx.x; t < 4096; t += 512) base[t] = lk[t];
}

// ---------------------------------------------------------------------------
// Stage 2: sorted greedy NMS with on-the-fly 2-way merge (main 8192 asc via
// merge-path, tail 208 sorted in LDS) and wave0-only in-chunk resolve.
// UNCHANGED.
// ---------------------------------------------------------------------------
__device__ __forceinline__ unsigned long long getB_(
    const unsigned long long* tailL, int p1, int x)
{
    int t = p1 + x;
    return (t < 256) ? tailL[t] : ~0ULL;
}

__global__ __launch_bounds__(256) void nms_k(
    const float4* __restrict__ boxes,
    const float* __restrict__ scores,
    const int* __restrict__ labels,
    const unsigned long long* __restrict__ keys,
    float* __restrict__ out)
{
    __shared__ unsigned long long tailL[256];
    __shared__ unsigned long long aw[512];
    __shared__ float4 sbox[256];
    __shared__ float  sar[256];
    __shared__ int    sidx[256];
    __shared__ float4 kboxL[kMaxOut];
    __shared__ float  kareaL[kMaxOut];
    __shared__ int    kidxL[kMaxOut];
    __shared__ unsigned long long ballS[4];
    __shared__ int p0S, p1S, kcS, doneS, stopS;

    const int b = blockIdx.x, tid = threadIdx.x;
    const unsigned long long* mainA = keys + ((size_t)b << 14);
    const float4* bx = boxes + (size_t)b * kN;

    if (tid == 0) { p0S = 0; p1S = 0; kcS = 0; doneS = 0; }

    // ---- sort the 208-key tail (pad to 256) in LDS, ascending bitonic ----
    tailL[tid] = (tid < kTail) ? mainA[kMain + tid] : ~0ULL;
    __syncthreads();
    for (int size = 2; size <= 256; size <<= 1) {
        for (int stride = size >> 1; stride > 0; stride >>= 1) {
            if (tid < 128) {
                int i = ((tid & ~(stride - 1)) << 1) | (tid & (stride - 1));
                int j = i + stride;
                bool desc = (i & size) != 0;
                unsigned long long a = tailL[i], c = tailL[j];
                bool sw = desc ? (c > a) : (a > c);
                if (sw) { tailL[i] = c; tailL[j] = a; }
            }
            __syncthreads();
        }
    }

    int kc = 0;
    for (int c = 0; c < 33; ++c) {
        int p0 = p0S, p1 = p1S;          // synced by previous barrier
        aw[tid]       = (p0 + tid       < kMain) ? mainA[p0 + tid]       : ~0ULL;
        aw[tid + 256] = (p0 + tid + 256 < kMain) ? mainA[p0 + tid + 256] : ~0ULL;
        __syncthreads();                  // B1: window visible

        // ---- merge-path: thread t produces merged element at diagonal t ----
        int d = tid;
        int lo = 0, hi = d;
        while (lo < hi) {
            int mid = (lo + hi) >> 1;     // mid < d
            bool c2 = getB_(tailL, p1, d - mid - 1) < aw[mid];
            if (c2) hi = mid; else lo = mid + 1;
        }
        unsigned long long av = aw[lo];
        unsigned long long bv = getB_(tailL, p1, d - lo);
        unsigned long long key = (av <= bv) ? av : bv;   // A-first ties (pads only)

        bool alive = (key != ~0ULL);
        int idx = alive ? (int)(key & 0xFFFFFFFFULL) : 0;
        float4 cb = bx[idx];
        float ac = (cb.z - cb.x) * (cb.w - cb.y);

        // ---- pre-test vs keeps from previous chunks ----
        if (alive) {
            for (int k = 0; k < kc; ++k) {
                float4 kb = kboxL[k];
                float t0 = fmaxf(kb.x, cb.x), t1 = fmaxf(kb.y, cb.y);
                float b0 = fminf(kb.z, cb.z), b1 = fminf(kb.w, cb.w);
                float inter = fmaxf(b0 - t0, 0.f) * fmaxf(b1 - t1, 0.f);
                float iou = inter / (kareaL[k] + ac - inter + 1e-9f);
                if (iou > kIouTh) { alive = false; break; }
            }
        }
        sbox[tid] = cb; sar[tid] = ac; sidx[tid] = idx;
        unsigned long long mm = __ballot((int)alive);
        if ((tid & 63) == 0) ballS[tid >> 6] = mm;
        if (tid == 0) {
            stopS = (key == ~0ULL);       // diagonal-0 key == min remaining
            // advance pointers: merge-path at diagonal 256
            int lo2 = 0, hi2 = 256;
            while (lo2 < hi2) {
                int mid = (lo2 + hi2) >> 1;
                bool c2 = getB_(tailL, p1, 255 - mid) < aw[mid];
                if (c2) hi2 = mid; else lo2 = mid + 1;
            }
            p0S = p0 + lo2; p1S = p1 + (256 - lo2);
        }
        __syncthreads();                  // B2: sbox/ball/stop/pointers visible
        if (stopS) break;

        // ---- wave0-only in-chunk greedy resolve (no block barriers) ----
        if (tid < 64) {
            const int lane = tid;
            unsigned a4 = 0;
#pragma unroll
            for (int j = 0; j < 4; ++j)
                a4 |= (unsigned)((ballS[j] >> lane) & 1ULL) << j;
            int kcl = kc;
            while (true) {
                int jF = -1, lF = 0;
#pragma unroll
                for (int j = 0; j < 4; ++j) {
                    if (jF < 0) {
                        unsigned long long m2 = __ballot((int)((a4 >> j) & 1u));
                        if (m2) { jF = j; lF = __ffsll((unsigned long long)m2) - 1; }
                    }
                }
                if (jF < 0) break;
                int cs = (jF << 6) + lF;
                float4 kb = sbox[cs];
                float kar = sar[cs];
                if (lane == 0) {
                    kboxL[kcl] = kb; kareaL[kcl] = kar; kidxL[kcl] = sidx[cs];
                }
                if (lane == lF) a4 &= ~(1u << jF);
                ++kcl;
                if (kcl == kMaxOut) break;
#pragma unroll
                for (int j = 0; j < 4; ++j) {
                    if ((a4 >> j) & 1u) {
                        float4 cb2 = sbox[lane + (j << 6)];
                        float ac2 = sar[lane + (j << 6)];
                        float t0 = fmaxf(kb.x, cb2.x), t1 = fmaxf(kb.y, cb2.y);
                        float b0 = fminf(kb.z, cb2.z), b1 = fminf(kb.w, cb2.w);
                        float inter = fmaxf(b0 - t0, 0.f) * fmaxf(b1 - t1, 0.f);
                        float iou = inter / (kar + ac2 - inter + 1e-9f);
                        if (iou > kIouTh) a4 &= ~(1u << j);
                    }
                }
            }
            if (lane == 0) { kcS = kcl; if (kcl == kMaxOut) doneS = 1; }
        }
        __syncthreads();                  // B3: keeps visible
        kc = kcS;
        if (doneS) break;
    }

    // ---- epilogue: parallel output ----
    int kcf = kcS;
    if (tid < kMaxOut) {
        if (tid < kcf) {
            int idx = kidxL[tid];
            ((float4*)out)[b * kMaxOut + tid] = kboxL[tid];
            out[kB * kMaxOut * 4 + b * kMaxOut + tid] =
                (float)labels[(size_t)b * kN + idx];
            out[kB * kMaxOut * 5 + b * kMaxOut + tid] =
                scores[(size_t)b * kN + idx];
        } else {
            ((float4*)out)[b * kMaxOut + tid] = make_float4(0.f, 0.f, 0.f, 0.f);
            out[kB * kMaxOut * 4 + b * kMaxOut + tid] = -1.0f;
            out[kB * kMaxOut * 5 + b * kMaxOut + tid] = 0.0f;
        }
    }
}

extern "C" void kernel_launch(void* const* d_in, const int* in_sizes, int n_in,
                              void* d_out, int out_size, void* d_ws, size_t ws_size,
                              hipStream_t stream)
{
    const float* preds = (const float*)d_in[0];
    const float* anchors = (const float*)d_in[1];
    float* out = (float*)d_out;

    char* ws = (char*)d_ws;
    float4* boxes = (float4*)ws;                                   // 8.60 MB
    float* scores = (float*)(ws + (size_t)kB * kN * 16);           // 2.15 MB
    int* labels = (int*)(ws + (size_t)kB * kN * 20);               // 2.15 MB
    unsigned long long* keys =
        (unsigned long long*)(ws + (size_t)kB * kN * 24);          // 64*16384*8

    decode2_k<<<(kB * kN) / 64, 256, 0, stream>>>(preds, anchors, boxes, scores, labels, keys);
    sortL_k<<<kB * 4, 512, 0, stream>>>(keys);
    lm2_k<4096><<<kB * 2, 512, 0, stream>>>(keys);
    gce_k<<<(kB * 4096) / 256, 256, 0, stream>>>(keys);
    lm2_k<8192><<<kB * 2, 512, 0, stream>>>(keys);
    nms_k<<<kB, 256, 0, stream>>>(boxes, scores, labels, keys, out);
}